// Round 5
// baseline (600.549 us; speedup 1.0000x reference)
//
#include <hip/hip_runtime.h>
#include <hip/hip_bf16.h>
#include <math.h>

#define N 4096
#define DIN 256
#define DOUT 256
#define KK 3
#define CAP 512

typedef int i4 __attribute__((ext_vector_type(4)));

// ---------------- Pass 1: wx[k] = x @ W_t[k]  (fp32 tiled GEMM) ----------------
__global__ __launch_bounds__(256) void gemm_wx(const float* __restrict__ x,
                                               const float* __restrict__ Wt,
                                               float* __restrict__ wx) {
    __shared__ float As[16][68];   // [BK][BM+pad], transposed x tile
    __shared__ float Bs[16][68];   // [BK][BN+pad]
    const int k  = blockIdx.z;
    const int n0 = blockIdx.y * 64;
    const int d0 = blockIdx.x * 64;
    const int tx = threadIdx.x, ty = threadIdx.y;
    const int t  = ty * 16 + tx;
    float acc[4][4] = {};
    const float* xA = x + (size_t)(n0 + (t >> 2)) * DIN + ((t & 3) * 4);
    const float* wB = Wt + (size_t)k * DIN * DOUT + (size_t)(t >> 4) * DOUT + d0 + (t & 15) * 4;
    for (int k0 = 0; k0 < DIN; k0 += 16) {
        float4 xa = *(const float4*)(xA + k0);
        float4 wb = *(const float4*)(wB + (size_t)k0 * DOUT);
        const int r = t >> 2, c = (t & 3) * 4;
        As[c + 0][r] = xa.x; As[c + 1][r] = xa.y; As[c + 2][r] = xa.z; As[c + 3][r] = xa.w;
        *(float4*)&Bs[t >> 4][(t & 15) * 4] = wb;
        __syncthreads();
#pragma unroll
        for (int kk = 0; kk < 16; ++kk) {
            float4 a = *(const float4*)&As[kk][ty * 4];
            float4 b = *(const float4*)&Bs[kk][tx * 4];
            float av[4] = {a.x, a.y, a.z, a.w};
            float bv[4] = {b.x, b.y, b.z, b.w};
#pragma unroll
            for (int i = 0; i < 4; ++i)
#pragma unroll
                for (int j = 0; j < 4; ++j)
                    acc[i][j] = fmaf(av[i], bv[j], acc[i][j]);
        }
        __syncthreads();
    }
#pragma unroll
    for (int i = 0; i < 4; ++i) {
        const int row = n0 + ty * 4 + i;
        float4 o = {acc[i][0], acc[i][1], acc[i][2], acc[i][3]};
        *(float4*)(wx + ((size_t)k * N + row) * DOUT + d0 + tx * 4) = o;
    }
}

// ---------------- Pass 2: al/ar = wx[k] @ W_{l,r}[k].T  ([K][N][4]) ----------------
__global__ __launch_bounds__(256) void alar_kernel(const float* __restrict__ wx,
                                                   const float* __restrict__ Wl,
                                                   const float* __restrict__ Wr,
                                                   float* __restrict__ al,
                                                   float* __restrict__ ar) {
    const int k    = blockIdx.y;
    const int wid  = threadIdx.x >> 6;
    const int lane = threadIdx.x & 63;
    const int n    = blockIdx.x * 4 + wid;
    float4 wxv = *(const float4*)(wx + ((size_t)k * N + n) * DOUT + lane * 4);
#pragma unroll
    for (int j = 0; j < 4; ++j) {
        float4 wl = *(const float4*)(Wl + ((size_t)k * 4 + j) * DOUT + lane * 4);
        float4 wr = *(const float4*)(Wr + ((size_t)k * 4 + j) * DOUT + lane * 4);
        float pl = wxv.x * wl.x + wxv.y * wl.y + wxv.z * wl.z + wxv.w * wl.w;
        float pr = wxv.x * wr.x + wxv.y * wr.y + wxv.z * wr.z + wxv.w * wr.w;
#pragma unroll
        for (int o = 32; o > 0; o >>= 1) { pl += __shfl_xor(pl, o); pr += __shfl_xor(pr, o); }
        if (lane == 0) {
            al[((size_t)k * N + n) * 4 + j] = pl;
            ar[((size_t)k * N + n) * 4 + j] = pr;
        }
    }
}

// ---------------- Pass 3: union-CSR build from 6 dense masks (402 MB stream) ----------------
__global__ __launch_bounds__(256) void build_kernel(const int* __restrict__ sup,
                                                    const int* __restrict__ att,
                                                    int* __restrict__ row_cnt,
                                                    unsigned int* __restrict__ entries) {
    const int n = blockIdx.x;
    __shared__ int scnt;
    if (threadIdx.x == 0) scnt = 0;
    __syncthreads();
    const int t = threadIdx.x;
#pragma unroll
    for (int i = 0; i < 4; ++i) {
        const int m0 = i * 1024 + t * 4;
        // streamed once, zero reuse -> nontemporal to avoid L2/L3 thrash
        i4 a0 = __builtin_nontemporal_load((const i4*)(att + ((size_t)0 * N + n) * N + m0));
        i4 a1 = __builtin_nontemporal_load((const i4*)(att + ((size_t)1 * N + n) * N + m0));
        i4 a2 = __builtin_nontemporal_load((const i4*)(att + ((size_t)2 * N + n) * N + m0));
        i4 s0 = __builtin_nontemporal_load((const i4*)(sup + ((size_t)0 * N + n) * N + m0));
        i4 s1 = __builtin_nontemporal_load((const i4*)(sup + ((size_t)1 * N + n) * N + m0));
        i4 s2 = __builtin_nontemporal_load((const i4*)(sup + ((size_t)2 * N + n) * N + m0));
#pragma unroll
        for (int j = 0; j < 4; ++j) {
            unsigned bits = 0;
            if (a0[j]) bits |= 1u;
            if (a1[j]) bits |= 2u;
            if (a2[j]) bits |= 4u;
            if (s0[j]) bits |= 8u;
            if (s1[j]) bits |= 16u;
            if (s2[j]) bits |= 32u;
            if (bits) {
                int pos = atomicAdd(&scnt, 1);
                if (pos < CAP) entries[(size_t)n * CAP + pos] = (unsigned)(m0 + j) | (bits << 12);
            }
        }
    }
    __syncthreads();
    if (threadIdx.x == 0) row_cnt[n] = min(scnt, CAP);
}

// ---------------- Pass 4: per-row sparse softmax + PV + ELU ----------------
__global__ __launch_bounds__(256) void attn_kernel(const float* __restrict__ wx,
                                                   const float* __restrict__ al,
                                                   const float* __restrict__ ar,
                                                   const int* __restrict__ row_cnt,
                                                   const unsigned int* __restrict__ entries,
                                                   float* __restrict__ out) {
    const int n = blockIdx.x;
    const int t = threadIdx.x;
    __shared__ unsigned int ent[CAP];
    __shared__ float sc[CAP];
    __shared__ float red[8];
    const int cnt = row_cnt[n];
    for (int e = t; e < cnt; e += 256) ent[e] = entries[(size_t)n * CAP + e];
    __syncthreads();
    float acc = 0.f;
    for (int k = 0; k < KK; ++k) {
        const float4 alv = *(const float4*)(al + ((size_t)k * N + n) * 4);
        const float* ark = ar + (size_t)k * N * 4;
        const unsigned kb = 8u << k;
        // phase 1: scores for this k over union entries; score==0 <=> invalid (matches ref)
        float lmax = -INFINITY;
        for (int e = t; e < cnt; e += 256) {
            const unsigned v = ent[e];
            const int m = v & 0xFFFu;
            const unsigned bits = v >> 12;
            float4 arv = *(const float4*)(ark + (size_t)m * 4);
            float s = 0.f;
            if (bits & 1u) s += alv.x + arv.x;
            if (bits & 2u) s += alv.y + arv.y;
            if (bits & 4u) s += alv.z + arv.z;
            if (bits & kb) s += alv.w + arv.w;
            sc[e] = s;
            if (s != 0.f) lmax = fmaxf(lmax, s);
        }
#pragma unroll
        for (int o = 32; o > 0; o >>= 1) lmax = fmaxf(lmax, __shfl_xor(lmax, o));
        if ((t & 63) == 0) red[t >> 6] = lmax;
        __syncthreads();
        const float rmax = fmaxf(fmaxf(red[0], red[1]), fmaxf(red[2], red[3]));
        __syncthreads();
        if (rmax != -INFINITY) {   // uniform branch: at least one valid edge
            float lsum = 0.f;
            for (int e = t; e < cnt; e += 256) {
                const float s = sc[e];
                const float p = (s != 0.f) ? __expf(s - rmax) : 0.f;
                sc[e] = p;
                lsum += p;
            }
#pragma unroll
            for (int o = 32; o > 0; o >>= 1) lsum += __shfl_xor(lsum, o);
            if ((t & 63) == 0) red[t >> 6] = lsum;
            __syncthreads();
            const float denom = red[0] + red[1] + red[2] + red[3];
            const float inv = 1.f / denom;
            for (int e = t; e < cnt; e += 256) sc[e] *= inv;
            __syncthreads();
            // PV: thread t owns output column t; gather valid wx rows (coalesced 1KB/row)
            const float* wxk = wx + (size_t)k * N * DOUT + t;
            for (int e = 0; e < cnt; ++e) {
                const float p = sc[e];
                if (p == 0.f) continue;
                const int m = ent[e] & 0xFFFu;
                acc = fmaf(p, wxk[(size_t)m * DOUT], acc);
            }
            __syncthreads();   // sc reused next k
        }
    }
    out[(size_t)n * DOUT + t] = (acc > 0.f) ? acc : expm1f(acc);
}

extern "C" void kernel_launch(void* const* d_in, const int* in_sizes, int n_in,
                              void* d_out, int out_size, void* d_ws, size_t ws_size,
                              hipStream_t stream) {
    const float* x   = (const float*)d_in[0];
    const int*   sup = (const int*)d_in[1];
    const int*   att = (const int*)d_in[2];
    const float* Wt  = (const float*)d_in[3];
    const float* Wl  = (const float*)d_in[4];
    const float* Wr  = (const float*)d_in[5];
    float* out = (float*)d_out;

    char* ws = (char*)d_ws;
    float* wx        = (float*)(ws + 0);            // 3*4096*256*4 = 12,582,912 B
    float* al        = (float*)(ws + 12582912);     //   196,608 B
    float* ar        = (float*)(ws + 12779520);     //   196,608 B
    int*   row_cnt   = (int*)  (ws + 12976128);     //    16,384 B
    unsigned int* entries = (unsigned int*)(ws + 12992512); // 8,388,608 B  (total ~21.4 MB)

    gemm_wx<<<dim3(DOUT / 64, N / 64, KK), dim3(16, 16), 0, stream>>>(x, Wt, wx);
    alar_kernel<<<dim3(N / 4, KK), 256, 0, stream>>>(wx, Wl, Wr, al, ar);
    build_kernel<<<N, 256, 0, stream>>>(sup, att, row_cnt, entries);
    attn_kernel<<<N, 256, 0, stream>>>(wx, al, ar, row_cnt, entries, out);
}

// Round 6
// 526.276 us; speedup vs baseline: 1.1411x; 1.1411x over previous
//
#include <hip/hip_runtime.h>
#include <hip/hip_bf16.h>
#include <math.h>

#define N 4096
#define DIN 256
#define DOUT 256
#define KK 3
#define CAP 512

typedef int i4 __attribute__((ext_vector_type(4)));

// ---------------- Pass 1: wx[k] = x @ W_t[k]  (fp32 tiled GEMM) ----------------
__global__ __launch_bounds__(256) void gemm_wx(const float* __restrict__ x,
                                               const float* __restrict__ Wt,
                                               float* __restrict__ wx) {
    __shared__ float As[16][68];   // [BK][BM+pad], transposed x tile
    __shared__ float Bs[16][68];   // [BK][BN+pad]
    const int k  = blockIdx.z;
    const int n0 = blockIdx.y * 64;
    const int d0 = blockIdx.x * 64;
    const int tx = threadIdx.x, ty = threadIdx.y;
    const int t  = ty * 16 + tx;
    float acc[4][4] = {};
    const float* xA = x + (size_t)(n0 + (t >> 2)) * DIN + ((t & 3) * 4);
    const float* wB = Wt + (size_t)k * DIN * DOUT + (size_t)(t >> 4) * DOUT + d0 + (t & 15) * 4;
    for (int k0 = 0; k0 < DIN; k0 += 16) {
        float4 xa = *(const float4*)(xA + k0);
        float4 wb = *(const float4*)(wB + (size_t)k0 * DOUT);
        const int r = t >> 2, c = (t & 3) * 4;
        As[c + 0][r] = xa.x; As[c + 1][r] = xa.y; As[c + 2][r] = xa.z; As[c + 3][r] = xa.w;
        *(float4*)&Bs[t >> 4][(t & 15) * 4] = wb;
        __syncthreads();
#pragma unroll
        for (int kk = 0; kk < 16; ++kk) {
            float4 a = *(const float4*)&As[kk][ty * 4];
            float4 b = *(const float4*)&Bs[kk][tx * 4];
            float av[4] = {a.x, a.y, a.z, a.w};
            float bv[4] = {b.x, b.y, b.z, b.w};
#pragma unroll
            for (int i = 0; i < 4; ++i)
#pragma unroll
                for (int j = 0; j < 4; ++j)
                    acc[i][j] = fmaf(av[i], bv[j], acc[i][j]);
        }
        __syncthreads();
    }
#pragma unroll
    for (int i = 0; i < 4; ++i) {
        const int row = n0 + ty * 4 + i;
        float4 o = {acc[i][0], acc[i][1], acc[i][2], acc[i][3]};
        *(float4*)(wx + ((size_t)k * N + row) * DOUT + d0 + tx * 4) = o;
    }
}

// ---------------- Pass 2: al/ar = wx[k] @ W_{l,r}[k].T  ([K][N][4]) ----------------
__global__ __launch_bounds__(256) void alar_kernel(const float* __restrict__ wx,
                                                   const float* __restrict__ Wl,
                                                   const float* __restrict__ Wr,
                                                   float* __restrict__ al,
                                                   float* __restrict__ ar) {
    const int k    = blockIdx.y;
    const int wid  = threadIdx.x >> 6;
    const int lane = threadIdx.x & 63;
    const int n    = blockIdx.x * 4 + wid;
    float4 wxv = *(const float4*)(wx + ((size_t)k * N + n) * DOUT + lane * 4);
#pragma unroll
    for (int j = 0; j < 4; ++j) {
        float4 wl = *(const float4*)(Wl + ((size_t)k * 4 + j) * DOUT + lane * 4);
        float4 wr = *(const float4*)(Wr + ((size_t)k * 4 + j) * DOUT + lane * 4);
        float pl = wxv.x * wl.x + wxv.y * wl.y + wxv.z * wl.z + wxv.w * wl.w;
        float pr = wxv.x * wr.x + wxv.y * wr.y + wxv.z * wr.z + wxv.w * wr.w;
#pragma unroll
        for (int o = 32; o > 0; o >>= 1) { pl += __shfl_xor(pl, o); pr += __shfl_xor(pr, o); }
        if (lane == 0) {
            al[((size_t)k * N + n) * 4 + j] = pl;
            ar[((size_t)k * N + n) * 4 + j] = pr;
        }
    }
}

// ---------------- Pass 3: union-CSR build from 6 dense masks (402 MB stream) ----------------
__global__ __launch_bounds__(256) void build_kernel(const int* __restrict__ sup,
                                                    const int* __restrict__ att,
                                                    int* __restrict__ row_cnt,
                                                    unsigned int* __restrict__ entries) {
    const int n = blockIdx.x;
    __shared__ int scnt;
    if (threadIdx.x == 0) scnt = 0;
    __syncthreads();
    const int t = threadIdx.x;
#pragma unroll
    for (int i = 0; i < 4; ++i) {
        const int m0 = i * 1024 + t * 4;
        // streamed once, zero reuse -> nontemporal to avoid L2/L3 thrash
        i4 a0 = __builtin_nontemporal_load((const i4*)(att + ((size_t)0 * N + n) * N + m0));
        i4 a1 = __builtin_nontemporal_load((const i4*)(att + ((size_t)1 * N + n) * N + m0));
        i4 a2 = __builtin_nontemporal_load((const i4*)(att + ((size_t)2 * N + n) * N + m0));
        i4 s0 = __builtin_nontemporal_load((const i4*)(sup + ((size_t)0 * N + n) * N + m0));
        i4 s1 = __builtin_nontemporal_load((const i4*)(sup + ((size_t)1 * N + n) * N + m0));
        i4 s2 = __builtin_nontemporal_load((const i4*)(sup + ((size_t)2 * N + n) * N + m0));
#pragma unroll
        for (int j = 0; j < 4; ++j) {
            unsigned bits = 0;
            if (a0[j]) bits |= 1u;
            if (a1[j]) bits |= 2u;
            if (a2[j]) bits |= 4u;
            if (s0[j]) bits |= 8u;
            if (s1[j]) bits |= 16u;
            if (s2[j]) bits |= 32u;
            if (bits) {
                int pos = atomicAdd(&scnt, 1);
                if (pos < CAP) entries[(size_t)n * CAP + pos] = (unsigned)(m0 + j) | (bits << 12);
            }
        }
    }
    __syncthreads();
    if (threadIdx.x == 0) row_cnt[n] = min(scnt, CAP);
}

// ---------------- Pass 4: per-row sparse softmax + PV + ELU ----------------
// PV restructured for latency hiding: lane l owns columns 4l..4l+3 (float4),
// each of the 4 waves processes entries e === w (mod 4), branch-free, 4x unrolled.
__global__ __launch_bounds__(256) void attn_kernel(const float* __restrict__ wx,
                                                   const float* __restrict__ al,
                                                   const float* __restrict__ ar,
                                                   const int* __restrict__ row_cnt,
                                                   const unsigned int* __restrict__ entries,
                                                   float* __restrict__ out) {
    const int n = blockIdx.x;
    const int t = threadIdx.x;
    const int w = t >> 6;      // wave id 0..3
    const int lane = t & 63;   // lane in wave
    __shared__ unsigned int ent[CAP];
    __shared__ float sc[CAP];
    __shared__ float red[8];
    __shared__ float4 accbuf[4][64];
    const int cnt = row_cnt[n];
    for (int e = t; e < cnt; e += 256) ent[e] = entries[(size_t)n * CAP + e];
    __syncthreads();
    float4 acc4 = {0.f, 0.f, 0.f, 0.f};   // per-wave partial, cols 4*lane..4*lane+3
    for (int k = 0; k < KK; ++k) {
        const float4 alv = *(const float4*)(al + ((size_t)k * N + n) * 4);
        const float* ark = ar + (size_t)k * N * 4;
        const unsigned kb = 8u << k;
        // phase 1: scores for this k over union entries; score==0 <=> invalid (matches ref)
        float lmax = -INFINITY;
        for (int e = t; e < cnt; e += 256) {
            const unsigned v = ent[e];
            const int m = v & 0xFFFu;
            const unsigned bits = v >> 12;
            float4 arv = *(const float4*)(ark + (size_t)m * 4);
            float s = 0.f;
            if (bits & 1u) s += alv.x + arv.x;
            if (bits & 2u) s += alv.y + arv.y;
            if (bits & 4u) s += alv.z + arv.z;
            if (bits & kb) s += alv.w + arv.w;
            sc[e] = s;
            if (s != 0.f) lmax = fmaxf(lmax, s);
        }
#pragma unroll
        for (int o = 32; o > 0; o >>= 1) lmax = fmaxf(lmax, __shfl_xor(lmax, o));
        if ((t & 63) == 0) red[t >> 6] = lmax;
        __syncthreads();
        const float rmax = fmaxf(fmaxf(red[0], red[1]), fmaxf(red[2], red[3]));
        __syncthreads();
        if (rmax != -INFINITY) {   // uniform branch: at least one valid edge
            float lsum = 0.f;
            for (int e = t; e < cnt; e += 256) {
                const float s = sc[e];
                const float p = (s != 0.f) ? __expf(s - rmax) : 0.f;
                sc[e] = p;
                lsum += p;
            }
#pragma unroll
            for (int o = 32; o > 0; o >>= 1) lsum += __shfl_xor(lsum, o);
            if ((t & 63) == 0) red[t >> 6] = lsum;
            __syncthreads();   // sc[] (exp) + red complete
            const float inv = 1.f / (red[0] + red[1] + red[2] + red[3]);
            // PV: wave w handles entries w, w+4, w+8, ... ; one float4 row-chunk per lane.
            // Branch-free (p==0 contributes nothing), 4x unrolled -> 4 loads in flight.
            const float4* wxk4 = (const float4*)(wx + (size_t)k * N * DOUT) + lane;
            float4 pacc = {0.f, 0.f, 0.f, 0.f};
            int e = w;
            for (; e + 12 < cnt; e += 16) {
                const float p0 = sc[e], p1 = sc[e + 4], p2 = sc[e + 8], p3 = sc[e + 12];
                const int m0 = ent[e] & 0xFFF, m1 = ent[e + 4] & 0xFFF,
                          m2 = ent[e + 8] & 0xFFF, m3 = ent[e + 12] & 0xFFF;
                const float4 v0 = wxk4[(size_t)m0 * 64];
                const float4 v1 = wxk4[(size_t)m1 * 64];
                const float4 v2 = wxk4[(size_t)m2 * 64];
                const float4 v3 = wxk4[(size_t)m3 * 64];
                pacc.x = fmaf(p0, v0.x, pacc.x); pacc.y = fmaf(p0, v0.y, pacc.y);
                pacc.z = fmaf(p0, v0.z, pacc.z); pacc.w = fmaf(p0, v0.w, pacc.w);
                pacc.x = fmaf(p1, v1.x, pacc.x); pacc.y = fmaf(p1, v1.y, pacc.y);
                pacc.z = fmaf(p1, v1.z, pacc.z); pacc.w = fmaf(p1, v1.w, pacc.w);
                pacc.x = fmaf(p2, v2.x, pacc.x); pacc.y = fmaf(p2, v2.y, pacc.y);
                pacc.z = fmaf(p2, v2.z, pacc.z); pacc.w = fmaf(p2, v2.w, pacc.w);
                pacc.x = fmaf(p3, v3.x, pacc.x); pacc.y = fmaf(p3, v3.y, pacc.y);
                pacc.z = fmaf(p3, v3.z, pacc.z); pacc.w = fmaf(p3, v3.w, pacc.w);
            }
            for (; e < cnt; e += 4) {
                const float p = sc[e];
                const float4 v = wxk4[(size_t)(ent[e] & 0xFFF) * 64];
                pacc.x = fmaf(p, v.x, pacc.x); pacc.y = fmaf(p, v.y, pacc.y);
                pacc.z = fmaf(p, v.z, pacc.z); pacc.w = fmaf(p, v.w, pacc.w);
            }
            acc4.x = fmaf(inv, pacc.x, acc4.x);
            acc4.y = fmaf(inv, pacc.y, acc4.y);
            acc4.z = fmaf(inv, pacc.z, acc4.z);
            acc4.w = fmaf(inv, pacc.w, acc4.w);
            __syncthreads();   // sc reused next k
        }
    }
    // cross-wave reduce (4 partials per column group) + ELU + store
    accbuf[w][lane] = acc4;
    __syncthreads();
    if (t < 64) {
        const float4 s0 = accbuf[0][t], s1 = accbuf[1][t], s2 = accbuf[2][t], s3 = accbuf[3][t];
        float4 r;
        r.x = (s0.x + s1.x) + (s2.x + s3.x);
        r.y = (s0.y + s1.y) + (s2.y + s3.y);
        r.z = (s0.z + s1.z) + (s2.z + s3.z);
        r.w = (s0.w + s1.w) + (s2.w + s3.w);
        r.x = (r.x > 0.f) ? r.x : expm1f(r.x);
        r.y = (r.y > 0.f) ? r.y : expm1f(r.y);
        r.z = (r.z > 0.f) ? r.z : expm1f(r.z);
        r.w = (r.w > 0.f) ? r.w : expm1f(r.w);
        *(float4*)(out + (size_t)n * DOUT + t * 4) = r;
    }
}

extern "C" void kernel_launch(void* const* d_in, const int* in_sizes, int n_in,
                              void* d_out, int out_size, void* d_ws, size_t ws_size,
                              hipStream_t stream) {
    const float* x   = (const float*)d_in[0];
    const int*   sup = (const int*)d_in[1];
    const int*   att = (const int*)d_in[2];
    const float* Wt  = (const float*)d_in[3];
    const float* Wl  = (const float*)d_in[4];
    const float* Wr  = (const float*)d_in[5];
    float* out = (float*)d_out;

    char* ws = (char*)d_ws;
    float* wx        = (float*)(ws + 0);            // 3*4096*256*4 = 12,582,912 B
    float* al        = (float*)(ws + 12582912);     //   196,608 B
    float* ar        = (float*)(ws + 12779520);     //   196,608 B
    int*   row_cnt   = (int*)  (ws + 12976128);     //    16,384 B
    unsigned int* entries = (unsigned int*)(ws + 12992512); // 8,388,608 B  (total ~21.4 MB)

    gemm_wx<<<dim3(DOUT / 64, N / 64, KK), dim3(16, 16), 0, stream>>>(x, Wt, wx);
    alar_kernel<<<dim3(N / 4, KK), 256, 0, stream>>>(wx, Wl, Wr, al, ar);
    build_kernel<<<N, 256, 0, stream>>>(sup, att, row_cnt, entries);
    attn_kernel<<<N, 256, 0, stream>>>(wx, al, ar, row_cnt, entries, out);
}

// Round 7
// 470.395 us; speedup vs baseline: 1.2767x; 1.1188x over previous
//
#include <hip/hip_runtime.h>
#include <hip/hip_bf16.h>
#include <math.h>

#define N 4096
#define DIN 256
#define DOUT 256
#define KK 3
#define CAP 512

typedef int i4 __attribute__((ext_vector_type(4)));

// ---------------- Pass 1: wx[k] = x @ W_t[k]  (fp32 tiled GEMM) ----------------
__global__ __launch_bounds__(256) void gemm_wx(const float* __restrict__ x,
                                               const float* __restrict__ Wt,
                                               float* __restrict__ wx) {
    __shared__ float As[16][68];   // [BK][BM+pad], transposed x tile
    __shared__ float Bs[16][68];   // [BK][BN+pad]
    const int k  = blockIdx.z;
    const int n0 = blockIdx.y * 64;
    const int d0 = blockIdx.x * 64;
    const int tx = threadIdx.x, ty = threadIdx.y;
    const int t  = ty * 16 + tx;
    float acc[4][4] = {};
    const float* xA = x + (size_t)(n0 + (t >> 2)) * DIN + ((t & 3) * 4);
    const float* wB = Wt + (size_t)k * DIN * DOUT + (size_t)(t >> 4) * DOUT + d0 + (t & 15) * 4;
    for (int k0 = 0; k0 < DIN; k0 += 16) {
        float4 xa = *(const float4*)(xA + k0);
        float4 wb = *(const float4*)(wB + (size_t)k0 * DOUT);
        const int r = t >> 2, c = (t & 3) * 4;
        As[c + 0][r] = xa.x; As[c + 1][r] = xa.y; As[c + 2][r] = xa.z; As[c + 3][r] = xa.w;
        *(float4*)&Bs[t >> 4][(t & 15) * 4] = wb;
        __syncthreads();
#pragma unroll
        for (int kk = 0; kk < 16; ++kk) {
            float4 a = *(const float4*)&As[kk][ty * 4];
            float4 b = *(const float4*)&Bs[kk][tx * 4];
            float av[4] = {a.x, a.y, a.z, a.w};
            float bv[4] = {b.x, b.y, b.z, b.w};
#pragma unroll
            for (int i = 0; i < 4; ++i)
#pragma unroll
                for (int j = 0; j < 4; ++j)
                    acc[i][j] = fmaf(av[i], bv[j], acc[i][j]);
        }
        __syncthreads();
    }
#pragma unroll
    for (int i = 0; i < 4; ++i) {
        const int row = n0 + ty * 4 + i;
        float4 o = {acc[i][0], acc[i][1], acc[i][2], acc[i][3]};
        *(float4*)(wx + ((size_t)k * N + row) * DOUT + d0 + tx * 4) = o;
    }
}

// ---------------- Pass 2: al/ar = wx[k] @ W_{l,r}[k].T  ([K][N][4]) ----------------
__global__ __launch_bounds__(256) void alar_kernel(const float* __restrict__ wx,
                                                   const float* __restrict__ Wl,
                                                   const float* __restrict__ Wr,
                                                   float* __restrict__ al,
                                                   float* __restrict__ ar) {
    const int k    = blockIdx.y;
    const int wid  = threadIdx.x >> 6;
    const int lane = threadIdx.x & 63;
    const int n    = blockIdx.x * 4 + wid;
    float4 wxv = *(const float4*)(wx + ((size_t)k * N + n) * DOUT + lane * 4);
#pragma unroll
    for (int j = 0; j < 4; ++j) {
        float4 wl = *(const float4*)(Wl + ((size_t)k * 4 + j) * DOUT + lane * 4);
        float4 wr = *(const float4*)(Wr + ((size_t)k * 4 + j) * DOUT + lane * 4);
        float pl = wxv.x * wl.x + wxv.y * wl.y + wxv.z * wl.z + wxv.w * wl.w;
        float pr = wxv.x * wr.x + wxv.y * wr.y + wxv.z * wr.z + wxv.w * wr.w;
#pragma unroll
        for (int o = 32; o > 0; o >>= 1) { pl += __shfl_xor(pl, o); pr += __shfl_xor(pr, o); }
        if (lane == 0) {
            al[((size_t)k * N + n) * 4 + j] = pl;
            ar[((size_t)k * N + n) * 4 + j] = pr;
        }
    }
}

// ---------------- Pass 3: union-CSR build from 6 dense masks (402 MB stream) ----------------
__global__ __launch_bounds__(256) void build_kernel(const int* __restrict__ sup,
                                                    const int* __restrict__ att,
                                                    int* __restrict__ row_cnt,
                                                    unsigned int* __restrict__ entries) {
    const int n = blockIdx.x;
    __shared__ int scnt;
    if (threadIdx.x == 0) scnt = 0;
    __syncthreads();
    const int t = threadIdx.x;
#pragma unroll
    for (int i = 0; i < 4; ++i) {
        const int m0 = i * 1024 + t * 4;
        // streamed once, zero reuse -> nontemporal to avoid L2/L3 thrash
        i4 a0 = __builtin_nontemporal_load((const i4*)(att + ((size_t)0 * N + n) * N + m0));
        i4 a1 = __builtin_nontemporal_load((const i4*)(att + ((size_t)1 * N + n) * N + m0));
        i4 a2 = __builtin_nontemporal_load((const i4*)(att + ((size_t)2 * N + n) * N + m0));
        i4 s0 = __builtin_nontemporal_load((const i4*)(sup + ((size_t)0 * N + n) * N + m0));
        i4 s1 = __builtin_nontemporal_load((const i4*)(sup + ((size_t)1 * N + n) * N + m0));
        i4 s2 = __builtin_nontemporal_load((const i4*)(sup + ((size_t)2 * N + n) * N + m0));
#pragma unroll
        for (int j = 0; j < 4; ++j) {
            unsigned bits = 0;
            if (a0[j]) bits |= 1u;
            if (a1[j]) bits |= 2u;
            if (a2[j]) bits |= 4u;
            if (s0[j]) bits |= 8u;
            if (s1[j]) bits |= 16u;
            if (s2[j]) bits |= 32u;
            if (bits) {
                int pos = atomicAdd(&scnt, 1);
                if (pos < CAP) entries[(size_t)n * CAP + pos] = (unsigned)(m0 + j) | (bits << 12);
            }
        }
    }
    __syncthreads();
    if (threadIdx.x == 0) row_cnt[n] = min(scnt, CAP);
}

// ---------------- Pass 4 (x3, one per k): sparse softmax + compacted PV ----------------
// Per-k dispatch keeps the gather working set to wx[k] (4.2 MB ~ per-XCD L2).
// Valid entries are compacted to LDS so the PV gather is branch-free over ~2/3 the list.
__global__ __launch_bounds__(256) void attn_k(const float* __restrict__ wx,
                                              const float* __restrict__ al,
                                              const float* __restrict__ ar,
                                              const int* __restrict__ row_cnt,
                                              const unsigned int* __restrict__ entries,
                                              float* __restrict__ out_acc,
                                              int k) {
    const int n = blockIdx.x;
    const int t = threadIdx.x;
    const int w = t >> 6;      // wave id 0..3
    const int lane = t & 63;   // lane in wave
    __shared__ unsigned int ent[CAP];
    __shared__ float sc[CAP];
    __shared__ unsigned short cent[CAP];
    __shared__ float cp[CAP];
    __shared__ float red[8];
    __shared__ int vcnt;
    __shared__ float4 accbuf[4][64];
    const int cnt = row_cnt[n];
    for (int e = t; e < cnt; e += 256) ent[e] = entries[(size_t)n * CAP + e];
    __syncthreads();
    const float4 alv = *(const float4*)(al + ((size_t)k * N + n) * 4);
    const float* ark = ar + (size_t)k * N * 4;
    const unsigned kb = 8u << k;
    // phase 1: scores over union entries; score==0 <=> invalid (matches ref)
    float lmax = -INFINITY;
    for (int e = t; e < cnt; e += 256) {
        const unsigned v = ent[e];
        const int m = v & 0xFFFu;
        const unsigned bits = v >> 12;
        float4 arv = *(const float4*)(ark + (size_t)m * 4);
        float s = 0.f;
        if (bits & 1u) s += alv.x + arv.x;
        if (bits & 2u) s += alv.y + arv.y;
        if (bits & 4u) s += alv.z + arv.z;
        if (bits & kb) s += alv.w + arv.w;
        sc[e] = s;
        if (s != 0.f) lmax = fmaxf(lmax, s);
    }
#pragma unroll
    for (int o = 32; o > 0; o >>= 1) lmax = fmaxf(lmax, __shfl_xor(lmax, o));
    if (lane == 0) red[w] = lmax;
    if (t == 0) vcnt = 0;
    __syncthreads();
    const float rmax = fmaxf(fmaxf(red[0], red[1]), fmaxf(red[2], red[3]));
    __syncthreads();
    float4 acc4 = {0.f, 0.f, 0.f, 0.f};
    if (rmax != -INFINITY) {   // uniform: at least one valid edge for this k
        // phase 2: compact valid (col, p) pairs; accumulate denom
        float lsum = 0.f;
        for (int e = t; e < cnt; e += 256) {
            const float s = sc[e];
            if (s != 0.f) {
                const float p = __expf(s - rmax);
                const int pos = atomicAdd(&vcnt, 1);
                cent[pos] = (unsigned short)(ent[e] & 0xFFFu);
                cp[pos] = p;
                lsum += p;
            }
        }
#pragma unroll
        for (int o = 32; o > 0; o >>= 1) lsum += __shfl_xor(lsum, o);
        if (lane == 0) red[4 + w] = lsum;
        __syncthreads();
        const float inv = 1.f / (red[4] + red[5] + red[6] + red[7]);
        const int vc = vcnt;
        // phase 3: PV gather over compacted list; wave w takes e === w (mod 4)
        const float4* wxk4 = (const float4*)(wx + (size_t)k * N * DOUT) + lane;
        float4 pacc = {0.f, 0.f, 0.f, 0.f};
        int e = w;
        for (; e + 12 < vc; e += 16) {
            const float p0 = cp[e], p1 = cp[e + 4], p2 = cp[e + 8], p3 = cp[e + 12];
            const int m0 = cent[e], m1 = cent[e + 4], m2 = cent[e + 8], m3 = cent[e + 12];
            const float4 v0 = wxk4[(size_t)m0 * 64];
            const float4 v1 = wxk4[(size_t)m1 * 64];
            const float4 v2 = wxk4[(size_t)m2 * 64];
            const float4 v3 = wxk4[(size_t)m3 * 64];
            pacc.x = fmaf(p0, v0.x, pacc.x); pacc.y = fmaf(p0, v0.y, pacc.y);
            pacc.z = fmaf(p0, v0.z, pacc.z); pacc.w = fmaf(p0, v0.w, pacc.w);
            pacc.x = fmaf(p1, v1.x, pacc.x); pacc.y = fmaf(p1, v1.y, pacc.y);
            pacc.z = fmaf(p1, v1.z, pacc.z); pacc.w = fmaf(p1, v1.w, pacc.w);
            pacc.x = fmaf(p2, v2.x, pacc.x); pacc.y = fmaf(p2, v2.y, pacc.y);
            pacc.z = fmaf(p2, v2.z, pacc.z); pacc.w = fmaf(p2, v2.w, pacc.w);
            pacc.x = fmaf(p3, v3.x, pacc.x); pacc.y = fmaf(p3, v3.y, pacc.y);
            pacc.z = fmaf(p3, v3.z, pacc.z); pacc.w = fmaf(p3, v3.w, pacc.w);
        }
        for (; e < vc; e += 4) {
            const float p = cp[e];
            const float4 v = wxk4[(size_t)cent[e] * 64];
            pacc.x = fmaf(p, v.x, pacc.x); pacc.y = fmaf(p, v.y, pacc.y);
            pacc.z = fmaf(p, v.z, pacc.z); pacc.w = fmaf(p, v.w, pacc.w);
        }
        acc4.x = inv * pacc.x; acc4.y = inv * pacc.y;
        acc4.z = inv * pacc.z; acc4.w = inv * pacc.w;
    }
    // cross-wave reduce; k=0 writes (ws is poisoned), k>0 accumulates
    accbuf[w][lane] = acc4;
    __syncthreads();
    if (t < 64) {
        const float4 s0 = accbuf[0][t], s1 = accbuf[1][t], s2 = accbuf[2][t], s3 = accbuf[3][t];
        float4 r;
        r.x = (s0.x + s1.x) + (s2.x + s3.x);
        r.y = (s0.y + s1.y) + (s2.y + s3.y);
        r.z = (s0.z + s1.z) + (s2.z + s3.z);
        r.w = (s0.w + s1.w) + (s2.w + s3.w);
        float4* oa = (float4*)(out_acc + (size_t)n * DOUT) + t;
        if (k == 0) {
            *oa = r;
        } else {
            float4 old = *oa;
            r.x += old.x; r.y += old.y; r.z += old.z; r.w += old.w;
            *oa = r;
        }
    }
}

// ---------------- Pass 5: ELU finalize ----------------
__global__ __launch_bounds__(256) void elu_finalize(const float* __restrict__ out_acc,
                                                    float* __restrict__ out) {
    const int i = blockIdx.x * 256 + threadIdx.x;
    float4 v = ((const float4*)out_acc)[i];
    v.x = (v.x > 0.f) ? v.x : expm1f(v.x);
    v.y = (v.y > 0.f) ? v.y : expm1f(v.y);
    v.z = (v.z > 0.f) ? v.z : expm1f(v.z);
    v.w = (v.w > 0.f) ? v.w : expm1f(v.w);
    ((float4*)out)[i] = v;
}

extern "C" void kernel_launch(void* const* d_in, const int* in_sizes, int n_in,
                              void* d_out, int out_size, void* d_ws, size_t ws_size,
                              hipStream_t stream) {
    const float* x   = (const float*)d_in[0];
    const int*   sup = (const int*)d_in[1];
    const int*   att = (const int*)d_in[2];
    const float* Wt  = (const float*)d_in[3];
    const float* Wl  = (const float*)d_in[4];
    const float* Wr  = (const float*)d_in[5];
    float* out = (float*)d_out;

    char* ws = (char*)d_ws;
    float* wx        = (float*)(ws + 0);            // 3*4096*256*4 = 12,582,912 B
    float* al        = (float*)(ws + 12582912);     //   196,608 B
    float* ar        = (float*)(ws + 12779520);     //   196,608 B
    int*   row_cnt   = (int*)  (ws + 12976128);     //    16,384 B
    unsigned int* entries = (unsigned int*)(ws + 12992512); // 8,388,608 B
    float* out_acc   = (float*)(ws + 21381120);     // 4,194,304 B  (total ~25.6 MB)

    gemm_wx<<<dim3(DOUT / 64, N / 64, KK), dim3(16, 16), 0, stream>>>(x, Wt, wx);
    alar_kernel<<<dim3(N / 4, KK), 256, 0, stream>>>(wx, Wl, Wr, al, ar);
    build_kernel<<<N, 256, 0, stream>>>(sup, att, row_cnt, entries);
    for (int k = 0; k < KK; ++k)
        attn_k<<<N, 256, 0, stream>>>(wx, al, ar, row_cnt, entries, out_acc, k);
    elu_finalize<<<N * DOUT / 1024, 256, 0, stream>>>(out_acc, out);
}